// Round 1
// baseline (376.492 us; speedup 1.0000x reference)
//
#include <hip/hip_runtime.h>
#include <cstddef>

typedef __attribute__((ext_vector_type(4))) float  float4v;
typedef __attribute__((ext_vector_type(8))) short  short8v;
typedef __attribute__((ext_vector_type(4))) unsigned short ushort4v;
typedef __attribute__((ext_vector_type(8))) __bf16 bf16x8;
typedef __attribute__((ext_vector_type(4))) float  f32x4;

static constexpr int C_DIM = 768;
static constexpr int O_DIM = 768;
static constexpr int HW    = 64;
static constexpr int NEL   = 49152;  // 768*64 (both C*HW and O*HW)

__device__ __forceinline__ unsigned short f2bf(float f) {
  unsigned u = __builtin_bit_cast(unsigned, f);
  u += 0x7FFFu + ((u >> 16) & 1u);   // round-to-nearest-even
  return (unsigned short)(u >> 16);
}

// forward 8-pt real FFT (unnormalized), packed output [Re0,Re1,Re2,Re3,Re4,Im3,Im2,Im1]
__device__ __forceinline__ void rfft8p(float& x0, float& x1, float& x2, float& x3,
                                       float& x4, float& x5, float& x6, float& x7) {
  const float Cc = 0.70710678118654752f;
  float b0 = x0 + x4, b1 = x1 + x5, b2 = x2 + x6, b3 = x3 + x7;
  float d0 = x0 - x4, d1 = x1 - x5, d2 = x2 - x6, d3 = x3 - x7;
  float e0 = b0 + b2, e1 = b1 + b3, f0 = b0 - b2, f1 = b1 - b3;
  float t1 = Cc * (d1 - d3), t2 = Cc * (d1 + d3);
  x0 = e0 + e1; x4 = e0 - e1;
  x2 = f0;      x6 = -f1;
  x1 = d0 + t1; x7 = -(t2 + d2);
  x3 = d0 - t1; x5 = d2 - t2;
}

// inverse (unnormalized, e^{+}) of packed format -> 8 reals
__device__ __forceinline__ void irfft8p(float& x0, float& x1, float& x2, float& x3,
                                        float& x4, float& x5, float& x6, float& x7) {
  const float Cc = 0.70710678118654752f;
  float R0 = x0, R1 = x1, R2 = x2, R3 = x3, R4 = x4, I3 = x5, I2 = x6, I1 = x7;
  float p = R0 + R4, q = R0 - R4;
  float u = 2.f * R2, vv = 2.f * I2;
  float g1 = R1 + R3, g2 = R1 - R3, g3 = I1 + I3, g4 = I1 - I3;
  float E1 = p + u, E2 = p - u;
  float B1 = 2.f * g1, B2 = 2.f * g4;
  float A1 = 2.f * Cc * (g2 - g3), A2 = 2.f * Cc * (g2 + g3);
  x0 = E1 + B1;  x4 = E1 - B1;
  x2 = E2 - B2;  x6 = E2 + B2;
  x1 = q + A1 - vv;  x5 = q - A1 - vv;
  x3 = q - A2 + vv;  x7 = q + A2 + vv;
}

// 8-pt complex FFT (unnormalized). INV=false: e^{-}, INV=true: e^{+}
template<bool INV>
__device__ __forceinline__ void cfft8(
    float& r0, float& r1, float& r2, float& r3, float& r4, float& r5, float& r6, float& r7,
    float& i0, float& i1, float& i2, float& i3, float& i4, float& i5, float& i6, float& i7) {
  const float Cc = 0.70710678118654752f;
  float s0r = r0 + r4, s0i = i0 + i4, s1r = r2 + r6, s1i = i2 + i6;
  float t0r = r0 - r4, t0i = i0 - i4, t1r = r2 - r6, t1i = i2 - i6;
  float E0r = s0r + s1r, E0i = s0i + s1i;
  float E2r = s0r - s1r, E2i = s0i - s1i;
  float E1r, E1i, E3r, E3i;
  if (!INV) { E1r = t0r + t1i; E1i = t0i - t1r; E3r = t0r - t1i; E3i = t0i + t1r; }
  else      { E1r = t0r - t1i; E1i = t0i + t1r; E3r = t0r + t1i; E3i = t0i - t1r; }
  float u0r = r1 + r5, u0i = i1 + i5, u1r = r3 + r7, u1i = i3 + i7;
  float p0r = r1 - r5, p0i = i1 - i5, p1r = r3 - r7, p1i = i3 - i7;
  float O0r = u0r + u1r, O0i = u0i + u1i;
  float O2r = u0r - u1r, O2i = u0i - u1i;
  float O1r, O1i, O3r, O3i;
  if (!INV) { O1r = p0r + p1i; O1i = p0i - p1r; O3r = p0r - p1i; O3i = p0i + p1r; }
  else      { O1r = p0r - p1i; O1i = p0i + p1r; O3r = p0r + p1i; O3i = p0i - p1r; }
  float W1r, W1i, W2r, W2i, W3r, W3i;
  if (!INV) {
    W1r = Cc * (O1r + O1i); W1i = Cc * (O1i - O1r);
    W2r = O2i;              W2i = -O2r;
    W3r = Cc * (O3i - O3r); W3i = -Cc * (O3r + O3i);
  } else {
    W1r = Cc * (O1r - O1i); W1i = Cc * (O1i + O1r);
    W2r = -O2i;             W2i = O2r;
    W3r = -Cc * (O3r + O3i); W3i = Cc * (O3r - O3i);
  }
  r0 = E0r + O0r; i0 = E0i + O0i;  r4 = E0r - O0r; i4 = E0i - O0i;
  r1 = E1r + W1r; i1 = E1i + W1i;  r5 = E1r - W1r; i5 = E1i - W1i;
  r2 = E2r + W2r; i2 = E2i + W2i;  r6 = E2r - W2r; i6 = E2i - W2i;
  r3 = E3r + W3r; i3 = E3i + W3i;  r7 = E3r - W3r; i7 = E3i - W3i;
}

// ---------------- K0: proj_w f32 -> bf16 ----------------
__global__ __launch_bounds__(256) void k_convert_proj(const float* __restrict__ p,
                                                      unsigned short* __restrict__ pb) {
  int i = (blockIdx.x * 256 + threadIdx.x) * 4;
  float4v v = *(const float4v*)(p + i);
  ushort4v o;
#pragma unroll
  for (int r = 0; r < 4; ++r) o[r] = f2bf(v[r]);
  *(ushort4v*)(pb + i) = o;
}

// ---------------- K1: per-(b,c) 8x8 spectral filter, writes xT[b][hw][c] bf16 -------
#define ROWV(m) v[m][0], v[m][1], v[m][2], v[m][3], v[m][4], v[m][5], v[m][6], v[m][7]
#define COLV(w) v[0][w], v[1][w], v[2][w], v[3][w], v[4][w], v[5][w], v[6][w], v[7][w]

__global__ __launch_bounds__(256) void k_fft_filter(const float* __restrict__ x,
                                                    const float* __restrict__ wre,
                                                    const float* __restrict__ wim,
                                                    unsigned short* __restrict__ xT) {
  const int b = blockIdx.x / 3;
  const int c = (blockIdx.x % 3) * 256 + threadIdx.x;
  const float* xp = x + (size_t)b * NEL + c;
  float v[8][8];
#pragma unroll
  for (int m = 0; m < 8; ++m)
#pragma unroll
    for (int n = 0; n < 8; ++n) v[m][n] = xp[(size_t)(m * 8 + n) * C_DIM];

  // forward: rows (real fft, packed), then columns
#pragma unroll
  for (int m = 0; m < 8; ++m) rfft8p(ROWV(m));
  rfft8p(COLV(0));
  rfft8p(COLV(4));
  cfft8<false>(COLV(1), COLV(7));
  cfft8<false>(COLV(2), COLV(6));
  cfft8<false>(COLV(3), COLV(5));

  const float* wrp = wre + c * 40;
  const float* wip = wim + c * 40;
  const float S = 1.0f / 64.0f;
  // columns 0 and 4: Hermitian-packed along h, use symmetrized weight
  // (equivalent to irfft dropping Im of those bins)
#pragma unroll
  for (int w = 0; w <= 4; w += 4) {
    v[0][w] *= wrp[0 * 5 + w] * S;
    v[4][w] *= wrp[4 * 5 + w] * S;
#pragma unroll
    for (int h = 1; h <= 3; ++h) {
      float ar = (wrp[h * 5 + w] + wrp[(8 - h) * 5 + w]) * (0.5f * S);
      float ai = (wip[h * 5 + w] - wip[(8 - h) * 5 + w]) * (0.5f * S);
      float re = v[h][w], im = v[8 - h][w];
      v[h][w]     = re * ar - im * ai;
      v[8 - h][w] = re * ai + im * ar;
    }
  }
  // columns 1..3: full complex multiply, all 8 h rows
#pragma unroll
  for (int w = 1; w <= 3; ++w) {
#pragma unroll
    for (int h = 0; h < 8; ++h) {
      float ar = wrp[h * 5 + w] * S, ai = wip[h * 5 + w] * S;
      float re = v[h][w], im = v[h][8 - w];
      v[h][w]     = re * ar - im * ai;
      v[h][8 - w] = re * ai + im * ar;
    }
  }

  // inverse: columns then rows
  irfft8p(COLV(0));
  irfft8p(COLV(4));
  cfft8<true>(COLV(1), COLV(7));
  cfft8<true>(COLV(2), COLV(6));
  cfft8<true>(COLV(3), COLV(5));
#pragma unroll
  for (int m = 0; m < 8; ++m) irfft8p(ROWV(m));

  // store transposed: xT[b][s][c], s = m*8+n (coalesced 2B stores across c)
  unsigned short* op = xT + (size_t)b * NEL + c;
#pragma unroll
  for (int m = 0; m < 8; ++m)
#pragma unroll
    for (int n = 0; n < 8; ++n) op[(size_t)(m * 8 + n) * C_DIM] = f2bf(v[m][n]);
}

// ---------------- K2: per-b GEMM (768x64 = proj[768x768] @ xT[b]^T) + GN + GELU ------
__device__ __forceinline__ float gelu_exact(float t) {
  return 0.5f * t * (1.0f + erff(t * 0.70710678118654752f));
}

__global__ __launch_bounds__(512, 2) void k_gemm_gn(const unsigned short* __restrict__ projb,
                                                    const unsigned short* __restrict__ xT,
                                                    const float* __restrict__ gnw,
                                                    const float* __restrict__ gnb,
                                                    float* __restrict__ out) {
  const int b    = blockIdx.x;
  const int tid  = threadIdx.x;
  const int wid  = tid >> 6;        // 0..7, wave handles rows [wid*96, wid*96+96)
  const int lane = tid & 63;
  const int g    = lane >> 4;       // k-group within fragment
  const int l15  = lane & 15;

  const unsigned short* xTb = xT + (size_t)b * NEL;

  f32x4 acc[6][4];
#pragma unroll
  for (int mf = 0; mf < 6; ++mf)
#pragma unroll
    for (int nf = 0; nf < 4; ++nf) acc[mf][nf] = f32x4{0.f, 0.f, 0.f, 0.f};

#define LOADF(AF, BF, KS)                                                              \
  do {                                                                                 \
    const int kb_ = (KS) * 32;                                                         \
    _Pragma("unroll") for (int mf = 0; mf < 6; ++mf)                                   \
        AF[mf] = *(const short8v*)&projb[(wid * 96 + mf * 16 + l15) * 768 + kb_ + g * 8]; \
    _Pragma("unroll") for (int nf = 0; nf < 4; ++nf)                                   \
        BF[nf] = *(const short8v*)&xTb[(nf * 16 + l15) * 768 + kb_ + g * 8];           \
  } while (0)

#define MFMAS(AF, BF)                                                                  \
  do {                                                                                 \
    _Pragma("unroll") for (int mf = 0; mf < 6; ++mf)                                   \
        _Pragma("unroll") for (int nf = 0; nf < 4; ++nf)                               \
            acc[mf][nf] = __builtin_amdgcn_mfma_f32_16x16x32_bf16(                     \
                __builtin_bit_cast(bf16x8, AF[mf]), __builtin_bit_cast(bf16x8, BF[nf]),\
                acc[mf][nf], 0, 0, 0);                                                 \
  } while (0)

  short8v aA[6], bA[4], aB[6], bB[4];
  LOADF(aA, bA, 0);
#pragma unroll 1
  for (int ks = 0; ks < 22; ks += 2) {
    LOADF(aB, bB, ks + 1);
    MFMAS(aA, bA);
    LOADF(aA, bA, ks + 2);
    MFMAS(aB, bB);
  }
  LOADF(aB, bB, 23);
  MFMAS(aA, bA);
  MFMAS(aB, bB);

  // ---- GroupNorm stats over the whole 768x64 (deterministic in-block reduction) ----
  float s = 0.f, ss = 0.f;
#pragma unroll
  for (int mf = 0; mf < 6; ++mf)
#pragma unroll
    for (int nf = 0; nf < 4; ++nf)
#pragma unroll
      for (int r = 0; r < 4; ++r) {
        float t = acc[mf][nf][r];
        s += t;
        ss += t * t;
      }
#pragma unroll
  for (int off = 32; off > 0; off >>= 1) {
    s  += __shfl_xor(s, off, 64);
    ss += __shfl_xor(ss, off, 64);
  }
  __shared__ float redS[8], redQ[8];
  if (lane == 0) { redS[wid] = s; redQ[wid] = ss; }
  __syncthreads();
  float Stot = 0.f, Qtot = 0.f;
#pragma unroll
  for (int i = 0; i < 8; ++i) { Stot += redS[i]; Qtot += redQ[i]; }
  constexpr float invN = 1.0f / 49152.0f;
  const float mean = Stot * invN;
  const float inv  = rsqrtf(fmaxf(Qtot * invN - mean * mean, 0.f) + 1e-5f);

  // ---- apply GN + GELU, write out[b][n][o] (transposed) ----
  float* outb = out + (size_t)b * NEL;
#pragma unroll
  for (int mf = 0; mf < 6; ++mf) {
    const int o0 = wid * 96 + mf * 16 + g * 4;
    float4v gw = *(const float4v*)&gnw[o0];
    float4v gb = *(const float4v*)&gnb[o0];
#pragma unroll
    for (int nf = 0; nf < 4; ++nf) {
      const int n = nf * 16 + l15;
      float4v vo;
#pragma unroll
      for (int r = 0; r < 4; ++r) {
        float t = (acc[mf][nf][r] - mean) * inv;
        t = t * gw[r] + gb[r];
        vo[r] = gelu_exact(t);
      }
      *(float4v*)&outb[(size_t)n * O_DIM + o0] = vo;
    }
  }
#undef LOADF
#undef MFMAS
}

extern "C" void kernel_launch(void* const* d_in, const int* in_sizes, int n_in,
                              void* d_out, int out_size, void* d_ws, size_t ws_size,
                              hipStream_t stream) {
  const float* x   = (const float*)d_in[0];
  const float* wre = (const float*)d_in[1];
  const float* wim = (const float*)d_in[2];
  const float* pw  = (const float*)d_in[3];
  const float* gnw = (const float*)d_in[4];
  const float* gnb = (const float*)d_in[5];
  float* out = (float*)d_out;

  const int B = in_sizes[0] / NEL;  // 1024

  // workspace layout: [0, 1.2MB) proj bf16; [2MB, 2MB+96MB) xT bf16
  unsigned short* projb = (unsigned short*)d_ws;
  unsigned short* xT    = (unsigned short*)((char*)d_ws + (2u << 20));

  k_convert_proj<<<(O_DIM * C_DIM) / 1024, 256, 0, stream>>>(pw, projb);
  k_fft_filter<<<B * 3, 256, 0, stream>>>(x, wre, wim, xT);
  k_gemm_gn<<<B, 512, 0, stream>>>(projb, xT, gnw, gnb, out);
}

// Round 2
// 271.303 us; speedup vs baseline: 1.3877x; 1.3877x over previous
//
#include <hip/hip_runtime.h>
#include <cstddef>

typedef __attribute__((ext_vector_type(4))) float  float4v;
typedef __attribute__((ext_vector_type(8))) short  short8v;
typedef __attribute__((ext_vector_type(4))) unsigned short ushort4v;
typedef __attribute__((ext_vector_type(8))) unsigned short ushort8v;
typedef __attribute__((ext_vector_type(8))) __bf16 bf16x8;
typedef __attribute__((ext_vector_type(4))) float  f32x4;

static constexpr int C_DIM = 768;
static constexpr int O_DIM = 768;
static constexpr int NEL   = 49152;  // 768*64

__device__ __forceinline__ unsigned short f2bf(float f) {
  unsigned u = __builtin_bit_cast(unsigned, f);
  u += 0x7FFFu + ((u >> 16) & 1u);   // round-to-nearest-even
  return (unsigned short)(u >> 16);
}

// forward 8-pt real FFT (unnormalized), packed output [Re0,Re1,Re2,Re3,Re4,Im3,Im2,Im1]
__device__ __forceinline__ void rfft8p(float& x0, float& x1, float& x2, float& x3,
                                       float& x4, float& x5, float& x6, float& x7) {
  const float Cc = 0.70710678118654752f;
  float b0 = x0 + x4, b1 = x1 + x5, b2 = x2 + x6, b3 = x3 + x7;
  float d0 = x0 - x4, d1 = x1 - x5, d2 = x2 - x6, d3 = x3 - x7;
  float e0 = b0 + b2, e1 = b1 + b3, f0 = b0 - b2, f1 = b1 - b3;
  float t1 = Cc * (d1 - d3), t2 = Cc * (d1 + d3);
  x0 = e0 + e1; x4 = e0 - e1;
  x2 = f0;      x6 = -f1;
  x1 = d0 + t1; x7 = -(t2 + d2);
  x3 = d0 - t1; x5 = d2 - t2;
}

// inverse (unnormalized, e^{+}) of packed format -> 8 reals
__device__ __forceinline__ void irfft8p(float& x0, float& x1, float& x2, float& x3,
                                        float& x4, float& x5, float& x6, float& x7) {
  const float Cc = 0.70710678118654752f;
  float R0 = x0, R1 = x1, R2 = x2, R3 = x3, R4 = x4, I3 = x5, I2 = x6, I1 = x7;
  float p = R0 + R4, q = R0 - R4;
  float u = 2.f * R2, vv = 2.f * I2;
  float g1 = R1 + R3, g2 = R1 - R3, g3 = I1 + I3, g4 = I1 - I3;
  float E1 = p + u, E2 = p - u;
  float B1 = 2.f * g1, B2 = 2.f * g4;
  float A1 = 2.f * Cc * (g2 - g3), A2 = 2.f * Cc * (g2 + g3);
  x0 = E1 + B1;  x4 = E1 - B1;
  x2 = E2 - B2;  x6 = E2 + B2;
  x1 = q + A1 - vv;  x5 = q - A1 - vv;
  x3 = q - A2 + vv;  x7 = q + A2 + vv;
}

// 8-pt complex FFT (unnormalized). INV=false: e^{-}, INV=true: e^{+}
template<bool INV>
__device__ __forceinline__ void cfft8(
    float& r0, float& r1, float& r2, float& r3, float& r4, float& r5, float& r6, float& r7,
    float& i0, float& i1, float& i2, float& i3, float& i4, float& i5, float& i6, float& i7) {
  const float Cc = 0.70710678118654752f;
  float s0r = r0 + r4, s0i = i0 + i4, s1r = r2 + r6, s1i = i2 + i6;
  float t0r = r0 - r4, t0i = i0 - i4, t1r = r2 - r6, t1i = i2 - i6;
  float E0r = s0r + s1r, E0i = s0i + s1i;
  float E2r = s0r - s1r, E2i = s0i - s1i;
  float E1r, E1i, E3r, E3i;
  if (!INV) { E1r = t0r + t1i; E1i = t0i - t1r; E3r = t0r - t1i; E3i = t0i + t1r; }
  else      { E1r = t0r - t1i; E1i = t0i + t1r; E3r = t0r + t1i; E3i = t0i - t1r; }
  float u0r = r1 + r5, u0i = i1 + i5, u1r = r3 + r7, u1i = i3 + i7;
  float p0r = r1 - r5, p0i = i1 - i5, p1r = r3 - r7, p1i = i3 - i7;
  float O0r = u0r + u1r, O0i = u0i + u1i;
  float O2r = u0r - u1r, O2i = u0i - u1i;
  float O1r, O1i, O3r, O3i;
  if (!INV) { O1r = p0r + p1i; O1i = p0i - p1r; O3r = p0r - p1i; O3i = p0i + p1r; }
  else      { O1r = p0r - p1i; O1i = p0i + p1r; O3r = p0r + p1i; O3i = p0i - p1r; }
  float W1r, W1i, W2r, W2i, W3r, W3i;
  if (!INV) {
    W1r = Cc * (O1r + O1i); W1i = Cc * (O1i - O1r);
    W2r = O2i;              W2i = -O2r;
    W3r = Cc * (O3i - O3r); W3i = -Cc * (O3r + O3i);
  } else {
    W1r = Cc * (O1r - O1i); W1i = Cc * (O1i + O1r);
    W2r = -O2i;             W2i = O2r;
    W3r = -Cc * (O3r + O3i); W3i = Cc * (O3r - O3i);
  }
  r0 = E0r + O0r; i0 = E0i + O0i;  r4 = E0r - O0r; i4 = E0i - O0i;
  r1 = E1r + W1r; i1 = E1i + W1i;  r5 = E1r - W1r; i5 = E1i - W1i;
  r2 = E2r + W2r; i2 = E2i + W2i;  r6 = E2r - W2r; i6 = E2i - W2i;
  r3 = E3r + W3r; i3 = E3i + W3i;  r7 = E3r - W3r; i7 = E3i - W3i;
}

// ---------------- K0: proj_w f32 -> bf16 in MFMA B-fragment layout ----------------
// projB[ks=24][nf=48][lane=64][j=8]; lane=(g*16+l15) holds proj[o=nf*16+l15][c=ks*32+g*8+j]
__global__ __launch_bounds__(256) void k_convert_proj(const float* __restrict__ p,
                                                      unsigned short* __restrict__ pb) {
  int t = blockIdx.x * 256 + threadIdx.x;     // 73728 threads: o = t/96, cb = t%96
  int o = t / 96, cb = t - o * 96;            // cb indexes 8-wide c chunks
  const float* src = p + o * 768 + cb * 8;
  float4v v0 = *(const float4v*)(src);
  float4v v1 = *(const float4v*)(src + 4);
  ushort8v w;
#pragma unroll
  for (int r = 0; r < 4; ++r) { w[r] = f2bf(v0[r]); w[r + 4] = f2bf(v1[r]); }
  int ks = cb >> 2, g = cb & 3;
  int nf = o >> 4, l15 = o & 15;
  size_t off = ((size_t)(ks * 48 + nf) * 64 + g * 16 + l15) * 8;
  *(ushort8v*)(pb + off) = w;
}

// ---------------- K1: per-(b,c) 8x8 spectral filter, writes A-fragment layout -------
// xTf[b][ks=24][mf=4][lane=64][j=8]; lane=(g*16+l15) holds x_enh[b][c=ks*32+g*8+j][hw=mf*16+l15]
#define ROWV(m) v[m][0], v[m][1], v[m][2], v[m][3], v[m][4], v[m][5], v[m][6], v[m][7]
#define COLV(w) v[0][w], v[1][w], v[2][w], v[3][w], v[4][w], v[5][w], v[6][w], v[7][w]

__global__ __launch_bounds__(256) void k_fft_filter(const float* __restrict__ x,
                                                    const float* __restrict__ wre,
                                                    const float* __restrict__ wim,
                                                    unsigned short* __restrict__ xT) {
  const int b = blockIdx.x / 3;
  const int c = (blockIdx.x % 3) * 256 + threadIdx.x;
  const float* xp = x + (size_t)b * NEL + c;
  float v[8][8];
#pragma unroll
  for (int m = 0; m < 8; ++m)
#pragma unroll
    for (int n = 0; n < 8; ++n) v[m][n] = xp[(size_t)(m * 8 + n) * C_DIM];

  // forward: rows (real fft, packed), then columns
#pragma unroll
  for (int m = 0; m < 8; ++m) rfft8p(ROWV(m));
  rfft8p(COLV(0));
  rfft8p(COLV(4));
  cfft8<false>(COLV(1), COLV(7));
  cfft8<false>(COLV(2), COLV(6));
  cfft8<false>(COLV(3), COLV(5));

  const float* wrp = wre + c * 40;
  const float* wip = wim + c * 40;
  const float S = 1.0f / 64.0f;
  // columns 0 and 4: Hermitian-packed along h, symmetrized weight
#pragma unroll
  for (int w = 0; w <= 4; w += 4) {
    v[0][w] *= wrp[0 * 5 + w] * S;
    v[4][w] *= wrp[4 * 5 + w] * S;
#pragma unroll
    for (int h = 1; h <= 3; ++h) {
      float ar = (wrp[h * 5 + w] + wrp[(8 - h) * 5 + w]) * (0.5f * S);
      float ai = (wip[h * 5 + w] - wip[(8 - h) * 5 + w]) * (0.5f * S);
      float re = v[h][w], im = v[8 - h][w];
      v[h][w]     = re * ar - im * ai;
      v[8 - h][w] = re * ai + im * ar;
    }
  }
  // columns 1..3: full complex multiply
#pragma unroll
  for (int w = 1; w <= 3; ++w) {
#pragma unroll
    for (int h = 0; h < 8; ++h) {
      float ar = wrp[h * 5 + w] * S, ai = wip[h * 5 + w] * S;
      float re = v[h][w], im = v[h][8 - w];
      v[h][w]     = re * ar - im * ai;
      v[h][8 - w] = re * ai + im * ar;
    }
  }

  // inverse: columns then rows
  irfft8p(COLV(0));
  irfft8p(COLV(4));
  cfft8<true>(COLV(1), COLV(7));
  cfft8<true>(COLV(2), COLV(6));
  cfft8<true>(COLV(3), COLV(5));
#pragma unroll
  for (int m = 0; m < 8; ++m) irfft8p(ROWV(m));

  // scatter-store into A-fragment layout (thread owns fixed ks,g,j)
  unsigned short* op = xT + (size_t)b * NEL + (c >> 5) * 2048 + ((c >> 3) & 3) * 128 + (c & 7);
#pragma unroll
  for (int m = 0; m < 8; ++m)
#pragma unroll
    for (int n = 0; n < 8; ++n) {
      const int hw = m * 8 + n;
      op[(hw >> 4) * 512 + (hw & 15) * 8] = f2bf(v[m][n]);
    }
}

// ---------------- K2: per-b GEMM (64x768 = xT[b] @ projB) + GN + GELU ------
__device__ __forceinline__ float gelu_fast(float x) {
  // tanh-form GELU: x * sigmoid(2*0.7978845608*(x + 0.044715 x^3)); max |err| ~3e-4
  float p = x * x;
  float q = fmaf(p, -0.1029434f, -2.3022082f);  // -(2u)*log2e coefficients
  float e = exp2f(x * q);
  return x * __builtin_amdgcn_rcpf(1.0f + e);
}

__global__ __launch_bounds__(512, 2) void k_gemm_gn(const unsigned short* __restrict__ projB,
                                                    const unsigned short* __restrict__ xTf,
                                                    const float* __restrict__ gnw,
                                                    const float* __restrict__ gnb,
                                                    float* __restrict__ out) {
  const int b    = blockIdx.x;
  const int tid  = threadIdx.x;
  const int wid  = tid >> 6;        // 0..7, wave owns o in [wid*96, wid*96+96)
  const int lane = tid & 63;
  const int g    = lane >> 4;
  const int l15  = lane & 15;

  const unsigned short* Ab = xTf + (size_t)b * NEL + lane * 8;          // + ks*2048 + mf*512
  const unsigned short* Bb = projB + ((size_t)(wid * 6) * 64 + lane) * 8; // + ks*24576 + nf*512

  f32x4 acc[4][6];
#pragma unroll
  for (int mf = 0; mf < 4; ++mf)
#pragma unroll
    for (int nf = 0; nf < 6; ++nf) acc[mf][nf] = f32x4{0.f, 0.f, 0.f, 0.f};

#define LOADF(AF, BF, KS)                                                    \
  do {                                                                       \
    _Pragma("unroll") for (int mf = 0; mf < 4; ++mf)                         \
        AF[mf] = *(const short8v*)&Ab[(KS) * 2048 + mf * 512];               \
    _Pragma("unroll") for (int nf = 0; nf < 6; ++nf)                         \
        BF[nf] = *(const short8v*)&Bb[(KS) * 24576 + nf * 512];              \
  } while (0)

#define MFMAS(AF, BF)                                                        \
  do {                                                                       \
    _Pragma("unroll") for (int mf = 0; mf < 4; ++mf)                         \
        _Pragma("unroll") for (int nf = 0; nf < 6; ++nf)                     \
            acc[mf][nf] = __builtin_amdgcn_mfma_f32_16x16x32_bf16(           \
                __builtin_bit_cast(bf16x8, AF[mf]), __builtin_bit_cast(bf16x8, BF[nf]),\
                acc[mf][nf], 0, 0, 0);                                       \
  } while (0)

  short8v aA[4], bA[6], aB[4], bB[6];
  LOADF(aA, bA, 0);
#pragma unroll 1
  for (int ks = 0; ks < 22; ks += 2) {
    LOADF(aB, bB, ks + 1);
    MFMAS(aA, bA);
    LOADF(aA, bA, ks + 2);
    MFMAS(aB, bB);
  }
  LOADF(aB, bB, 23);
  MFMAS(aA, bA);
  MFMAS(aB, bB);

  // ---- GroupNorm stats over the whole 768x64 (deterministic in-block reduction) ----
  float s = 0.f, ss = 0.f;
#pragma unroll
  for (int mf = 0; mf < 4; ++mf)
#pragma unroll
    for (int nf = 0; nf < 6; ++nf)
#pragma unroll
      for (int r = 0; r < 4; ++r) {
        float t = acc[mf][nf][r];
        s += t;
        ss += t * t;
      }
#pragma unroll
  for (int off = 32; off > 0; off >>= 1) {
    s  += __shfl_xor(s, off, 64);
    ss += __shfl_xor(ss, off, 64);
  }
  __shared__ float redS[8], redQ[8];
  if (lane == 0) { redS[wid] = s; redQ[wid] = ss; }
  __syncthreads();
  float Stot = 0.f, Qtot = 0.f;
#pragma unroll
  for (int i = 0; i < 8; ++i) { Stot += redS[i]; Qtot += redQ[i]; }
  constexpr float invN = 1.0f / 49152.0f;
  const float mean = Stot * invN;
  const float inv  = rsqrtf(fmaxf(Qtot * invN - mean * mean, 0.f) + 1e-5f);

  // ---- apply GN + GELU, write out[b][hw][o] (row-contiguous in o) ----
  float* outb = out + (size_t)b * NEL;
#pragma unroll
  for (int nf = 0; nf < 6; ++nf) {
    const int o = wid * 96 + nf * 16 + l15;
    const float gw = gnw[o], gb_ = gnb[o];
#pragma unroll
    for (int mf = 0; mf < 4; ++mf)
#pragma unroll
      for (int r = 0; r < 4; ++r) {
        const int hw = mf * 16 + g * 4 + r;
        float t = (acc[mf][nf][r] - mean) * inv;
        t = t * gw + gb_;
        outb[(size_t)hw * O_DIM + o] = gelu_fast(t);
      }
  }
#undef LOADF
#undef MFMAS
}

extern "C" void kernel_launch(void* const* d_in, const int* in_sizes, int n_in,
                              void* d_out, int out_size, void* d_ws, size_t ws_size,
                              hipStream_t stream) {
  const float* x   = (const float*)d_in[0];
  const float* wre = (const float*)d_in[1];
  const float* wim = (const float*)d_in[2];
  const float* pw  = (const float*)d_in[3];
  const float* gnw = (const float*)d_in[4];
  const float* gnb = (const float*)d_in[5];
  float* out = (float*)d_out;

  const int B = in_sizes[0] / NEL;  // 1024

  // workspace: [0, 1.2MB) projB bf16 fragments; [2MB, 2MB+96MB) xTf bf16 fragments
  unsigned short* projB = (unsigned short*)d_ws;
  unsigned short* xTf   = (unsigned short*)((char*)d_ws + (2u << 20));

  k_convert_proj<<<288, 256, 0, stream>>>(pw, projB);
  k_fft_filter<<<B * 3, 256, 0, stream>>>(x, wre, wim, xTf);
  k_gemm_gn<<<B, 512, 0, stream>>>(projB, xTf, gnw, gnb, out);
}

// Round 3
// 173.571 us; speedup vs baseline: 2.1691x; 1.5631x over previous
//
#include <hip/hip_runtime.h>
#include <cstddef>

typedef __attribute__((ext_vector_type(4))) float  float4v;
typedef __attribute__((ext_vector_type(8))) short  short8v;
typedef __attribute__((ext_vector_type(8))) unsigned short ushort8v;
typedef __attribute__((ext_vector_type(8))) __bf16 bf16x8;
typedef __attribute__((ext_vector_type(4))) float  f32x4;

static constexpr int C_DIM = 768;
static constexpr int O_DIM = 768;
static constexpr int NEL   = 49152;  // 768*64

__device__ __forceinline__ unsigned short f2bf(float f) {
  unsigned u = __builtin_bit_cast(unsigned, f);
  u += 0x7FFFu + ((u >> 16) & 1u);
  return (unsigned short)(u >> 16);
}

// forward 8-pt real FFT (unnormalized), packed output [Re0,Re1,Re2,Re3,Re4,Im3,Im2,Im1]
__device__ __forceinline__ void rfft8p(float& x0, float& x1, float& x2, float& x3,
                                       float& x4, float& x5, float& x6, float& x7) {
  const float Cc = 0.70710678118654752f;
  float b0 = x0 + x4, b1 = x1 + x5, b2 = x2 + x6, b3 = x3 + x7;
  float d0 = x0 - x4, d1 = x1 - x5, d2 = x2 - x6, d3 = x3 - x7;
  float e0 = b0 + b2, e1 = b1 + b3, f0 = b0 - b2, f1 = b1 - b3;
  float t1 = Cc * (d1 - d3), t2 = Cc * (d1 + d3);
  x0 = e0 + e1; x4 = e0 - e1;
  x2 = f0;      x6 = -f1;
  x1 = d0 + t1; x7 = -(t2 + d2);
  x3 = d0 - t1; x5 = d2 - t2;
}

__device__ __forceinline__ void irfft8p(float& x0, float& x1, float& x2, float& x3,
                                        float& x4, float& x5, float& x6, float& x7) {
  const float Cc = 0.70710678118654752f;
  float R0 = x0, R1 = x1, R2 = x2, R3 = x3, R4 = x4, I3 = x5, I2 = x6, I1 = x7;
  float p = R0 + R4, q = R0 - R4;
  float u = 2.f * R2, vv = 2.f * I2;
  float g1 = R1 + R3, g2 = R1 - R3, g3 = I1 + I3, g4 = I1 - I3;
  float E1 = p + u, E2 = p - u;
  float B1 = 2.f * g1, B2 = 2.f * g4;
  float A1 = 2.f * Cc * (g2 - g3), A2c_ = 2.f * Cc * (g2 + g3);
  x0 = E1 + B1;  x4 = E1 - B1;
  x2 = E2 - B2;  x6 = E2 + B2;
  x1 = q + A1 - vv;  x5 = q - A1 - vv;
  x3 = q - A2c_ + vv;  x7 = q + A2c_ + vv;
}

template<bool INV>
__device__ __forceinline__ void cfft8(
    float& r0, float& r1, float& r2, float& r3, float& r4, float& r5, float& r6, float& r7,
    float& i0, float& i1, float& i2, float& i3, float& i4, float& i5, float& i6, float& i7) {
  const float Cc = 0.70710678118654752f;
  float s0r = r0 + r4, s0i = i0 + i4, s1r = r2 + r6, s1i = i2 + i6;
  float t0r = r0 - r4, t0i = i0 - i4, t1r = r2 - r6, t1i = i2 - i6;
  float E0r = s0r + s1r, E0i = s0i + s1i;
  float E2r = s0r - s1r, E2i = s0i - s1i;
  float E1r, E1i, E3r, E3i;
  if (!INV) { E1r = t0r + t1i; E1i = t0i - t1r; E3r = t0r - t1i; E3i = t0i + t1r; }
  else      { E1r = t0r - t1i; E1i = t0i + t1r; E3r = t0r + t1i; E3i = t0i - t1r; }
  float u0r = r1 + r5, u0i = i1 + i5, u1r = r3 + r7, u1i = i3 + i7;
  float p0r = r1 - r5, p0i = i1 - i5, p1r = r3 - r7, p1i = i3 - i7;
  float O0r = u0r + u1r, O0i = u0i + u1i;
  float O2r = u0r - u1r, O2i = u0i - u1i;
  float O1r, O1i, O3r, O3i;
  if (!INV) { O1r = p0r + p1i; O1i = p0i - p1r; O3r = p0r - p1i; O3i = p0i + p1r; }
  else      { O1r = p0r - p1i; O1i = p0i + p1r; O3r = p0r + p1i; O3i = p0i - p1r; }
  float W1r, W1i, W2r, W2i, W3r, W3i;
  if (!INV) {
    W1r = Cc * (O1r + O1i); W1i = Cc * (O1i - O1r);
    W2r = O2i;              W2i = -O2r;
    W3r = Cc * (O3i - O3r); W3i = -Cc * (O3r + O3i);
  } else {
    W1r = Cc * (O1r - O1i); W1i = Cc * (O1i + O1r);
    W2r = -O2i;             W2i = O2r;
    W3r = -Cc * (O3r + O3i); W3i = Cc * (O3r - O3i);
  }
  r0 = E0r + O0r; i0 = E0i + O0i;  r4 = E0r - O0r; i4 = E0i - O0i;
  r1 = E1r + W1r; i1 = E1i + W1i;  r5 = E1r - W1r; i5 = E1i - W1i;
  r2 = E2r + W2r; i2 = E2i + W2i;  r6 = E2r - W2r; i6 = E2i - W2i;
  r3 = E3r + W3r; i3 = E3i + W3i;  r7 = E3r - W3r; i7 = E3i - W3i;
}

// ---------------- K0: proj_w f32 -> bf16 in MFMA B-fragment layout ----------------
__global__ __launch_bounds__(256) void k_convert_proj(const float* __restrict__ p,
                                                      unsigned short* __restrict__ pb) {
  int t = blockIdx.x * 256 + threadIdx.x;
  int o = t / 96, cb = t - o * 96;
  const float* src = p + o * 768 + cb * 8;
  float4v v0 = *(const float4v*)(src);
  float4v v1 = *(const float4v*)(src + 4);
  ushort8v w;
#pragma unroll
  for (int r = 0; r < 4; ++r) { w[r] = f2bf(v0[r]); w[r + 4] = f2bf(v1[r]); }
  int ks = cb >> 2, g = cb & 3;
  int nf = o >> 4, l15 = o & 15;
  size_t off = ((size_t)(ks * 48 + nf) * 64 + g * 16 + l15) * 8;
  *(ushort8v*)(pb + off) = w;
}

// ---------------- K0b: pre-transpose + symmetrize spectral weights ----------------
// wT0/wT1[k=40][c=768]; S folded in; w∈{0,4},h∈{1..3} symmetrized pairs.
__global__ __launch_bounds__(256) void k_prep_w(const float* __restrict__ wre,
                                                const float* __restrict__ wim,
                                                float* __restrict__ wT0,
                                                float* __restrict__ wT1) {
  int i = blockIdx.x * 256 + threadIdx.x;   // 40*768 = 30720
  if (i >= 40 * 768) return;
  int k = i / 768, c = i - k * 768;
  int h = k / 5, w = k - h * 5;
  const float S = 1.0f / 64.0f;
  const float* wr = wre + c * 40;
  const float* wi = wim + c * 40;
  float ar, ai;
  if (w == 0 || w == 4) {
    if (h == 0 || h == 4)      { ar = wr[k] * S; ai = 0.f; }
    else if (h <= 3)           { ar = (wr[h * 5 + w] + wr[(8 - h) * 5 + w]) * (0.5f * S);
                                 ai = (wi[h * 5 + w] - wi[(8 - h) * 5 + w]) * (0.5f * S); }
    else                       { ar = 0.f; ai = 0.f; }
  } else                       { ar = wr[k] * S; ai = wi[k] * S; }
  wT0[i] = ar; wT1[i] = ai;
}

// ---------------- fused: FFT-filter (into LDS) + GEMM + GN + GELU ----------------
__device__ __forceinline__ float gelu_fast(float x) {
  float p = x * x;
  float q = fmaf(p, -0.1029434f, -2.3022082f);
  float e = exp2f(x * q);
  return x * __builtin_amdgcn_rcpf(1.0f + e);
}

__device__ __forceinline__ void fft_tile(const float* __restrict__ xb, int c,
                                         const float* __restrict__ wT0,
                                         const float* __restrict__ wT1,
                                         unsigned short* A2) {
  float v[8][8];
#pragma unroll
  for (int m = 0; m < 8; ++m)
#pragma unroll
    for (int n = 0; n < 8; ++n) v[m][n] = xb[(m * 8 + n) * C_DIM + c];

#define ROWV(m) v[m][0], v[m][1], v[m][2], v[m][3], v[m][4], v[m][5], v[m][6], v[m][7]
#define COLV(w) v[0][w], v[1][w], v[2][w], v[3][w], v[4][w], v[5][w], v[6][w], v[7][w]
#pragma unroll
  for (int m = 0; m < 8; ++m) rfft8p(ROWV(m));
  rfft8p(COLV(0));
  rfft8p(COLV(4));
  cfft8<false>(COLV(1), COLV(7));
  cfft8<false>(COLV(2), COLV(6));
  cfft8<false>(COLV(3), COLV(5));

#define LR(k) wT0[(k) * 768 + c]
#define LI(k) wT1[(k) * 768 + c]
#pragma unroll
  for (int w = 0; w <= 4; w += 4) {
    v[0][w] *= LR(w);
    v[4][w] *= LR(20 + w);
#pragma unroll
    for (int h = 1; h <= 3; ++h) {
      float ar = LR(h * 5 + w), ai = LI(h * 5 + w);
      float re = v[h][w], im = v[8 - h][w];
      v[h][w]     = re * ar - im * ai;
      v[8 - h][w] = re * ai + im * ar;
    }
  }
#pragma unroll
  for (int w = 1; w <= 3; ++w) {
#pragma unroll
    for (int h = 0; h < 8; ++h) {
      float ar = LR(h * 5 + w), ai = LI(h * 5 + w);
      float re = v[h][w], im = v[h][8 - w];
      v[h][w]     = re * ar - im * ai;
      v[h][8 - w] = re * ai + im * ar;
    }
  }
#undef LR
#undef LI

  irfft8p(COLV(0));
  irfft8p(COLV(4));
  cfft8<true>(COLV(1), COLV(7));
  cfft8<true>(COLV(2), COLV(6));
  cfft8<true>(COLV(3), COLV(5));
#pragma unroll
  for (int m = 0; m < 8; ++m) irfft8p(ROWV(m));
#undef ROWV
#undef COLV

  // A2[hw][c] bf16 with byte XOR-swizzle ((hw&7)<<4): conflict-free write & b128 read
  char* base = (char*)A2;
#pragma unroll
  for (int m = 0; m < 8; ++m)
#pragma unroll
    for (int n = 0; n < 8; ++n) {
      const int hw = m * 8 + n;
      int off = (hw * 1536 + c * 2) ^ ((hw & 7) << 4);
      *(unsigned short*)(base + off) = f2bf(v[m][n]);
    }
}

__global__ __launch_bounds__(512, 2) void k_fused(const float* __restrict__ x,
                                                  const float* __restrict__ wT0,
                                                  const float* __restrict__ wT1,
                                                  const unsigned short* __restrict__ projB,
                                                  const float* __restrict__ gnw,
                                                  const float* __restrict__ gnb,
                                                  float* __restrict__ out) {
  __shared__ __align__(16) unsigned short A2[64 * 768];  // 96 KB
  __shared__ float redS[8], redQ[8];

  const int b    = blockIdx.x;
  const int tid  = threadIdx.x;
  const int wid  = tid >> 6;
  const int lane = tid & 63;
  const int g    = lane >> 4;
  const int l15  = lane & 15;

  const unsigned short* Bb = projB + ((size_t)(wid * 6) * 64 + lane) * 8;

#define LOADB(BF, KS)                                                        \
  do {                                                                       \
    _Pragma("unroll") for (int nf = 0; nf < 6; ++nf)                         \
        BF[nf] = *(const short8v*)&Bb[(KS) * 24576 + nf * 512];              \
  } while (0)

  // issue first two B k-steps before the FFT phase: latency hides under it
  short8v a0[4], b0[6], a1[4], b1[6], a2[4], b2[6];
  LOADB(b0, 0);
  LOADB(b1, 1);

  // ---- FFT phase: 768 channels -> LDS A-tile ----
  const float* xb = x + (size_t)b * NEL;
  fft_tile(xb, tid, wT0, wT1, A2);
  if (tid < 256) fft_tile(xb, 512 + tid, wT0, wT1, A2);
  __syncthreads();

  const char* A2c = (const char*)A2;
  const int swz = (l15 & 7) << 4;

#define LOADA(AF, KS)                                                        \
  do {                                                                       \
    _Pragma("unroll") for (int mf = 0; mf < 4; ++mf)                         \
        AF[mf] = *(const short8v*)(A2c +                                     \
            (((mf * 16 + l15) * 1536 + (KS) * 64 + g * 16) ^ swz));          \
  } while (0)

#define MFMAS(AF, BF)                                                        \
  do {                                                                       \
    _Pragma("unroll") for (int mf = 0; mf < 4; ++mf)                         \
        _Pragma("unroll") for (int nf = 0; nf < 6; ++nf)                     \
            acc[mf][nf] = __builtin_amdgcn_mfma_f32_16x16x32_bf16(           \
                __builtin_bit_cast(bf16x8, AF[mf]), __builtin_bit_cast(bf16x8, BF[nf]),\
                acc[mf][nf], 0, 0, 0);                                       \
  } while (0)

  f32x4 acc[4][6];
#pragma unroll
  for (int mf = 0; mf < 4; ++mf)
#pragma unroll
    for (int nf = 0; nf < 6; ++nf) acc[mf][nf] = f32x4{0.f, 0.f, 0.f, 0.f};

  LOADA(a0, 0);
  LOADA(a1, 1);
#pragma unroll 1
  for (int ks = 0; ks < 21; ks += 3) {
    LOADB(b2, ks + 2); LOADA(a2, ks + 2);
    MFMAS(a0, b0);
    LOADB(b0, ks + 3); LOADA(a0, ks + 3);
    MFMAS(a1, b1);
    LOADB(b1, ks + 4); LOADA(a1, ks + 4);
    MFMAS(a2, b2);
  }
  LOADB(b2, 23); LOADA(a2, 23);
  MFMAS(a0, b0);
  MFMAS(a1, b1);
  MFMAS(a2, b2);

  // ---- GroupNorm stats (deterministic in-block reduction) ----
  float s = 0.f, ss = 0.f;
#pragma unroll
  for (int mf = 0; mf < 4; ++mf)
#pragma unroll
    for (int nf = 0; nf < 6; ++nf)
#pragma unroll
      for (int r = 0; r < 4; ++r) {
        float t = acc[mf][nf][r];
        s += t;
        ss += t * t;
      }
#pragma unroll
  for (int off = 32; off > 0; off >>= 1) {
    s  += __shfl_xor(s, off, 64);
    ss += __shfl_xor(ss, off, 64);
  }
  if (lane == 0) { redS[wid] = s; redQ[wid] = ss; }
  __syncthreads();
  float Stot = 0.f, Qtot = 0.f;
#pragma unroll
  for (int i = 0; i < 8; ++i) { Stot += redS[i]; Qtot += redQ[i]; }
  constexpr float invN = 1.0f / 49152.0f;
  const float mean = Stot * invN;
  const float inv  = rsqrtf(fmaxf(Qtot * invN - mean * mean, 0.f) + 1e-5f);

  // ---- GN + GELU, write out[b][hw][o] ----
  float* outb = out + (size_t)b * NEL;
#pragma unroll
  for (int nf = 0; nf < 6; ++nf) {
    const int o = wid * 96 + nf * 16 + l15;
    const float gw = gnw[o], gb_ = gnb[o];
#pragma unroll
    for (int mf = 0; mf < 4; ++mf)
#pragma unroll
      for (int r = 0; r < 4; ++r) {
        const int hw = mf * 16 + g * 4 + r;
        float t = (acc[mf][nf][r] - mean) * inv;
        t = t * gw + gb_;
        outb[(size_t)hw * O_DIM + o] = gelu_fast(t);
      }
  }
#undef LOADA
#undef LOADB
#undef MFMAS
}

extern "C" void kernel_launch(void* const* d_in, const int* in_sizes, int n_in,
                              void* d_out, int out_size, void* d_ws, size_t ws_size,
                              hipStream_t stream) {
  const float* x   = (const float*)d_in[0];
  const float* wre = (const float*)d_in[1];
  const float* wim = (const float*)d_in[2];
  const float* pw  = (const float*)d_in[3];
  const float* gnw = (const float*)d_in[4];
  const float* gnb = (const float*)d_in[5];
  float* out = (float*)d_out;

  const int B = in_sizes[0] / NEL;  // 1024

  // workspace: [0,1.2MB) projB; [2MB,2MB+120KB) wT0; [2.25MB, +120KB) wT1
  unsigned short* projB = (unsigned short*)d_ws;
  float* wT0 = (float*)((char*)d_ws + (2u << 20));
  float* wT1 = (float*)((char*)d_ws + (2u << 20) + (256u << 10));

  k_convert_proj<<<288, 256, 0, stream>>>(pw, projB);
  k_prep_w<<<120, 256, 0, stream>>>(wre, wim, wT0, wT1);
  k_fused<<<B, 512, 0, stream>>>(x, wT0, wT1, projB, gnw, gnb, out);
}